// Round 1
// baseline (793.605 us; speedup 1.0000x reference)
//
#include <hip/hip_runtime.h>
#include <hip/hip_bf16.h>
#include <stdint.h>

#define M_TOK 32768
#define DIM   1024
#define ODIM  1024
#define NEXP  4
#define TOPK  2
#define KTOT  4096   // NEXP * DIM

#define BM 128
#define BN 128
#define BK 64

typedef unsigned short u16;
typedef __bf16 bf16x8 __attribute__((ext_vector_type(8)));
typedef float  f32x4  __attribute__((ext_vector_type(4)));

__device__ inline u16 f2bf(float f) {
  union { float f; unsigned u; } v; v.f = f;
  unsigned u = v.u;
  unsigned r = u + 0x7FFFu + ((u >> 16) & 1u);
  return (u16)(r >> 16);
}

__device__ inline unsigned pack2(float lo, float hi) {
  return (unsigned)f2bf(lo) | ((unsigned)f2bf(hi) << 16);
}

__device__ inline void async16(const void* g, void* l) {
  __builtin_amdgcn_global_load_lds(
      (const __attribute__((address_space(1))) unsigned int*)g,
      (__attribute__((address_space(3))) unsigned int*)l, 16, 0, 0);
}

// ---- pre-pass 1: x fp32 -> bf16 ----
__global__ void cvt_x(const float4* __restrict__ x, uint4* __restrict__ xb, int n8) {
  int i = blockIdx.x * blockDim.x + threadIdx.x;
  int stride = gridDim.x * blockDim.x;
  for (; i < n8; i += stride) {
    float4 a = x[2 * i];
    float4 b = x[2 * i + 1];
    uint4 o;
    o.x = pack2(a.x, a.y); o.y = pack2(a.z, a.w);
    o.z = pack2(b.x, b.y); o.w = pack2(b.z, b.w);
    xb[i] = o;
  }
}

// ---- pre-pass 2: W (E*D=4096, O=1024) fp32 -> Wt (O=1024, E*D=4096) bf16 ----
__global__ void cvt_wt(const float* __restrict__ W, u16* __restrict__ Wt) {
  __shared__ float t[32][33];
  int kk0 = blockIdx.x * 32, n0 = blockIdx.y * 32;
  int tx = threadIdx.x, ty = threadIdx.y;  // block (32,8)
#pragma unroll
  for (int j = 0; j < 32; j += 8)
    t[ty + j][tx] = W[(size_t)(kk0 + ty + j) * ODIM + n0 + tx];
  __syncthreads();
#pragma unroll
  for (int j = 0; j < 32; j += 8)
    Wt[(size_t)(n0 + ty + j) * KTOT + kk0 + tx] = f2bf(t[tx][ty + j]);
}

// ---- pre-pass 3: per-token per-expert combine coefficients ----
__global__ void coeffs(const float* __restrict__ ew, const int* __restrict__ tki,
                       float4* __restrict__ C) {
  int t = blockIdx.x * blockDim.x + threadIdx.x;
  if (t >= M_TOK) return;
  float c0 = 0.f, c1 = 0.f, c2 = 0.f, c3 = 0.f;
#pragma unroll
  for (int k = 0; k < TOPK; ++k) {
    int e = tki[t * TOPK + k] & 3;
    float w = ew[t * TOPK + k];
    c0 += (e == 0) ? w : 0.f;
    c1 += (e == 1) ? w : 0.f;
    c2 += (e == 2) ? w : 0.f;
    c3 += (e == 3) ? w : 0.f;
  }
  float4 v; v.x = c0; v.y = c1; v.z = c2; v.w = c3;
  C[t] = v;
}

// ---- main GEMM: out = sum_e diag(c_e) * (X @ W_e + b_e) ----
__global__ __launch_bounds__(256) void moe_gemm(
    const u16* __restrict__ Xb,   // [M_TOK][DIM] bf16
    const u16* __restrict__ Wt,   // [ODIM][KTOT] bf16 (transposed weights)
    const float* __restrict__ C,  // [M_TOK][NEXP]
    const float* __restrict__ bias,  // [NEXP][ODIM] fp32
    float* __restrict__ out)         // [M_TOK][ODIM] fp32
{
  __shared__ __align__(16) u16 As[BM * BK];
  __shared__ __align__(16) u16 Bs[BN * BK];
  const int tid = threadIdx.x;
  const int wid = tid >> 6, lane = tid & 63;
  const int brow = blockIdx.x * BM, bcol = blockIdx.y * BN;
  const int wr = wid >> 1, wc = wid & 1;   // 2x2 wave grid, 64x64 per wave
  const int frow = brow + wr * 64, fcol = bcol + wc * 64;

  f32x4 oacc[4][4], sacc[4][4];
#pragma unroll
  for (int m = 0; m < 4; ++m)
#pragma unroll
    for (int n = 0; n < 4; ++n) {
      oacc[m][n] = (f32x4){0.f, 0.f, 0.f, 0.f};
      sacc[m][n] = (f32x4){0.f, 0.f, 0.f, 0.f};
    }

  const int srow = lane >> 3;        // 0..7  (staging row within 8-row chunk)
  const int scol = (lane & 7) * 8;   // 0..63 step 8 (staging col, bf16 elems)

  for (int kt = 0; kt < KTOT / BK; ++kt) {
    const int kx = (kt & 15) * BK;   // col in Xb (wraps per expert segment)
    const int kw = kt * BK;          // col in Wt
    __syncthreads();
#pragma unroll
    for (int i = 0; i < 4; ++i) {
      int c = wid * 4 + i;
      const u16* g = Xb + (size_t)(brow + c * 8 + srow) * DIM + kx + scol;
      async16(g, &As[c * 512]);
    }
#pragma unroll
    for (int i = 0; i < 4; ++i) {
      int c = wid * 4 + i;
      const u16* g = Wt + (size_t)(bcol + c * 8 + srow) * KTOT + kw + scol;
      async16(g, &Bs[c * 512]);
    }
    __syncthreads();
#pragma unroll
    for (int kk = 0; kk < 2; ++kk) {
      bf16x8 af[4], bfr[4];
#pragma unroll
      for (int m = 0; m < 4; ++m)
        af[m] = *reinterpret_cast<const bf16x8*>(
            &As[(wr * 64 + m * 16 + (lane & 15)) * BK + kk * 32 + (lane >> 4) * 8]);
#pragma unroll
      for (int n = 0; n < 4; ++n)
        bfr[n] = *reinterpret_cast<const bf16x8*>(
            &Bs[(wc * 64 + n * 16 + (lane & 15)) * BK + kk * 32 + (lane >> 4) * 8]);
#pragma unroll
      for (int m = 0; m < 4; ++m)
#pragma unroll
        for (int n = 0; n < 4; ++n)
          sacc[m][n] = __builtin_amdgcn_mfma_f32_16x16x32_bf16(af[m], bfr[n], sacc[m][n], 0, 0, 0);
    }
    if ((kt & 15) == 15) {   // expert segment boundary
      const int e = kt >> 4;
#pragma unroll
      for (int m = 0; m < 4; ++m) {
        float cr[4];
#pragma unroll
        for (int r = 0; r < 4; ++r)
          cr[r] = C[(size_t)(frow + m * 16 + (lane >> 4) * 4 + r) * NEXP + e];
#pragma unroll
        for (int n = 0; n < 4; ++n) {
          float bb = bias[e * ODIM + fcol + n * 16 + (lane & 15)];
#pragma unroll
          for (int r = 0; r < 4; ++r)
            oacc[m][n][r] += cr[r] * (sacc[m][n][r] + bb);
          sacc[m][n] = (f32x4){0.f, 0.f, 0.f, 0.f};
        }
      }
    }
  }

  // epilogue: fp32 store
#pragma unroll
  for (int m = 0; m < 4; ++m)
#pragma unroll
    for (int n = 0; n < 4; ++n)
#pragma unroll
      for (int r = 0; r < 4; ++r)
        out[(size_t)(frow + m * 16 + (lane >> 4) * 4 + r) * ODIM + fcol + n * 16 + (lane & 15)] =
            oacc[m][n][r];
}

extern "C" void kernel_launch(void* const* d_in, const int* in_sizes, int n_in,
                              void* d_out, int out_size, void* d_ws, size_t ws_size,
                              hipStream_t stream) {
  const float* x    = (const float*)d_in[0];
  const float* ew   = (const float*)d_in[1];
  const int*   tki  = (const int*)d_in[2];
  const float* W    = (const float*)d_in[3];
  const float* bias = (const float*)d_in[4];
  float* out = (float*)d_out;

  u16*   xb = (u16*)d_ws;                                    // 67,108,864 B
  u16*   wt = (u16*)((char*)d_ws + 67108864);                // 8,388,608 B
  float* C  = (float*)((char*)d_ws + 67108864 + 8388608);    // 524,288 B

  cvt_x<<<4096, 256, 0, stream>>>((const float4*)x, (uint4*)xb, M_TOK * DIM / 8);
  cvt_wt<<<dim3(KTOT / 32, ODIM / 32), dim3(32, 8), 0, stream>>>(W, wt);
  coeffs<<<M_TOK / 256, 256, 0, stream>>>(ew, tki, (float4*)C);
  moe_gemm<<<dim3(M_TOK / BM, ODIM / BN), 256, 0, stream>>>(xb, wt, C, bias, out);
}

// Round 3
// 446.463 us; speedup vs baseline: 1.7775x; 1.7775x over previous
//
#include <hip/hip_runtime.h>
#include <hip/hip_bf16.h>
#include <stdint.h>

#define M_TOK 32768
#define DIM   1024
#define ODIM  1024
#define NEXP  4
#define TOPK  2
#define KTOT  4096   // NEXP * DIM

#define BM 128
#define BN 64
#define BK 64

typedef unsigned short u16;
typedef __bf16 bf16x8 __attribute__((ext_vector_type(8)));
typedef float  f32x4  __attribute__((ext_vector_type(4)));

__device__ inline u16 f2bf(float f) {
  union { float f; unsigned u; } v; v.f = f;
  unsigned u = v.u;
  unsigned r = u + 0x7FFFu + ((u >> 16) & 1u);
  return (u16)(r >> 16);
}

__device__ inline unsigned pack2(float lo, float hi) {
  return (unsigned)f2bf(lo) | ((unsigned)f2bf(hi) << 16);
}

__device__ inline void async16(const void* g, void* l) {
  __builtin_amdgcn_global_load_lds(
      (const __attribute__((address_space(1))) unsigned int*)g,
      (__attribute__((address_space(3))) unsigned int*)l, 16, 0, 0);
}

// ---- pre-pass 1: x fp32 -> bf16 ----
__global__ void cvt_x(const float4* __restrict__ x, uint4* __restrict__ xb, int n8) {
  int i = blockIdx.x * blockDim.x + threadIdx.x;
  int stride = gridDim.x * blockDim.x;
  for (; i < n8; i += stride) {
    float4 a = x[2 * i];
    float4 b = x[2 * i + 1];
    uint4 o;
    o.x = pack2(a.x, a.y); o.y = pack2(a.z, a.w);
    o.z = pack2(b.x, b.y); o.w = pack2(b.z, b.w);
    xb[i] = o;
  }
}

// ---- pre-pass 2: W (E*D=4096, O=1024) fp32 -> Wt (O=1024, E*D=4096) bf16 ----
__global__ void cvt_wt(const float* __restrict__ W, u16* __restrict__ Wt) {
  __shared__ float t[32][33];
  int kk0 = blockIdx.x * 32, n0 = blockIdx.y * 32;
  int tx = threadIdx.x, ty = threadIdx.y;  // block (32,8)
#pragma unroll
  for (int j = 0; j < 32; j += 8)
    t[ty + j][tx] = W[(size_t)(kk0 + ty + j) * ODIM + n0 + tx];
  __syncthreads();
#pragma unroll
  for (int j = 0; j < 32; j += 8)
    Wt[(size_t)(n0 + ty + j) * KTOT + kk0 + tx] = f2bf(t[tx][ty + j]);
}

// ---- pre-pass 3: per-token per-expert combine coefficients ----
__global__ void coeffs(const float* __restrict__ ew, const int* __restrict__ tki,
                       float4* __restrict__ C) {
  int t = blockIdx.x * blockDim.x + threadIdx.x;
  if (t >= M_TOK) return;
  float c0 = 0.f, c1 = 0.f, c2 = 0.f, c3 = 0.f;
#pragma unroll
  for (int k = 0; k < TOPK; ++k) {
    int e = tki[t * TOPK + k] & 3;
    float w = ew[t * TOPK + k];
    c0 += (e == 0) ? w : 0.f;
    c1 += (e == 1) ? w : 0.f;
    c2 += (e == 2) ? w : 0.f;
    c3 += (e == 3) ? w : 0.f;
  }
  float4 v; v.x = c0; v.y = c1; v.z = c2; v.w = c3;
  C[t] = v;
}

// ---- main GEMM: out = sum_e diag(c_e) * (X @ W_e + b_e) ----
// 256 threads, 2x2 waves, wave tile 64x32 (4x2 fragments).
// LDS tiles XOR-swizzled: linear global_load_lds dest + pre-swizzled global
// source column (((lane&7)^srow)*8 elems) + swizzled ds_read (byte ^ (row&7)<<4).
__global__ __launch_bounds__(256, 3) void moe_gemm(
    const u16* __restrict__ Xb,      // [M_TOK][DIM] bf16
    const u16* __restrict__ Wt,      // [ODIM][KTOT] bf16 (transposed weights)
    const float* __restrict__ C,     // [M_TOK][NEXP]
    const float* __restrict__ bias,  // [NEXP][ODIM] fp32
    float* __restrict__ out)         // [M_TOK][ODIM] fp32
{
  __shared__ __align__(16) u16 As[BM * BK];   // 16 KB
  __shared__ __align__(16) u16 Bs[BN * BK];   // 8 KB
  const int tid = threadIdx.x;
  const int wid = tid >> 6, lane = tid & 63;
  const int bcol = blockIdx.x * BN, brow = blockIdx.y * BM;
  const int wr = wid >> 1, wc = wid & 1;   // 2x2 wave grid; wave tile 64x32
  const int frow = brow + wr * 64, fcol = bcol + wc * 32;

  f32x4 oacc[4][2], sacc[4][2];
#pragma unroll
  for (int m = 0; m < 4; ++m)
#pragma unroll
    for (int n = 0; n < 2; ++n) {
      oacc[m][n] = (f32x4){0.f, 0.f, 0.f, 0.f};
      sacc[m][n] = (f32x4){0.f, 0.f, 0.f, 0.f};
    }

  const int srow = lane >> 3;                    // 0..7 (row within 8-row chunk)
  const int scol = ((lane & 7) ^ srow) * 8;      // pre-swizzled source col (elems)
  const int hi16 = (lane >> 4) * 16;             // fragment col byte (k-slot)
  const int swz  = (lane & 7) << 4;              // read-side XOR (row&7)<<4
  char* AsB = (char*)As;
  char* BsB = (char*)Bs;

  for (int kt = 0; kt < KTOT / BK; ++kt) {
    const int kx = (kt & 15) * BK;   // col in Xb (wraps per expert segment)
    const int kw = kt * BK;          // col in Wt
    __syncthreads();
    // stage A: 16 chunks of 8 rows, 4 per wave
#pragma unroll
    for (int i = 0; i < 4; ++i) {
      int c = wid * 4 + i;
      const u16* g = Xb + (size_t)(brow + c * 8 + srow) * DIM + kx + scol;
      async16(g, &As[c * 512]);
    }
    // stage B: 8 chunks of 8 rows, 2 per wave
#pragma unroll
    for (int i = 0; i < 2; ++i) {
      int c = wid * 2 + i;
      const u16* g = Wt + (size_t)(bcol + c * 8 + srow) * KTOT + kw + scol;
      async16(g, &Bs[c * 512]);
    }
    __syncthreads();
#pragma unroll
    for (int kk = 0; kk < 2; ++kk) {
      const int cb = (kk * 64 + hi16) ^ swz;   // swizzled column byte
      bf16x8 af[4], bfr[2];
#pragma unroll
      for (int m = 0; m < 4; ++m) {
        int row = wr * 64 + m * 16 + (lane & 15);
        af[m] = *reinterpret_cast<const bf16x8*>(AsB + row * 128 + cb);
      }
#pragma unroll
      for (int n = 0; n < 2; ++n) {
        int row = wc * 32 + n * 16 + (lane & 15);
        bfr[n] = *reinterpret_cast<const bf16x8*>(BsB + row * 128 + cb);
      }
#pragma unroll
      for (int m = 0; m < 4; ++m)
#pragma unroll
        for (int n = 0; n < 2; ++n)
          sacc[m][n] = __builtin_amdgcn_mfma_f32_16x16x32_bf16(af[m], bfr[n], sacc[m][n], 0, 0, 0);
    }
    if ((kt & 15) == 15) {   // expert segment boundary: fold into oacc
      const int e = kt >> 4;
#pragma unroll
      for (int m = 0; m < 4; ++m) {
        float cr[4];
#pragma unroll
        for (int r = 0; r < 4; ++r)
          cr[r] = C[(size_t)(frow + m * 16 + (lane >> 4) * 4 + r) * NEXP + e];
#pragma unroll
        for (int n = 0; n < 2; ++n) {
          float bb = bias[e * ODIM + fcol + n * 16 + (lane & 15)];
#pragma unroll
          for (int r = 0; r < 4; ++r)
            oacc[m][n][r] += cr[r] * (sacc[m][n][r] + bb);
          sacc[m][n] = (f32x4){0.f, 0.f, 0.f, 0.f};
        }
      }
    }
  }

  // epilogue: fp32 store
#pragma unroll
  for (int m = 0; m < 4; ++m)
#pragma unroll
    for (int n = 0; n < 2; ++n)
#pragma unroll
      for (int r = 0; r < 4; ++r)
        out[(size_t)(frow + m * 16 + (lane >> 4) * 4 + r) * ODIM + fcol + n * 16 + (lane & 15)] =
            oacc[m][n][r];
}

extern "C" void kernel_launch(void* const* d_in, const int* in_sizes, int n_in,
                              void* d_out, int out_size, void* d_ws, size_t ws_size,
                              hipStream_t stream) {
  const float* x    = (const float*)d_in[0];
  const float* ew   = (const float*)d_in[1];
  const int*   tki  = (const int*)d_in[2];
  const float* W    = (const float*)d_in[3];
  const float* bias = (const float*)d_in[4];
  float* out = (float*)d_out;

  u16*   xb = (u16*)d_ws;                                    // 67,108,864 B
  u16*   wt = (u16*)((char*)d_ws + 67108864);                // 8,388,608 B
  float* C  = (float*)((char*)d_ws + 67108864 + 8388608);    // 524,288 B

  cvt_x<<<4096, 256, 0, stream>>>((const float4*)x, (uint4*)xb, M_TOK * DIM / 8);
  cvt_wt<<<dim3(KTOT / 32, ODIM / 32), dim3(32, 8), 0, stream>>>(W, wt);
  coeffs<<<M_TOK / 256, 256, 0, stream>>>(ew, tki, (float4*)C);
  // grid.x = N-blocks (16): the 16 blocks sharing an A-panel are dispatch-adjacent
  moe_gemm<<<dim3(ODIM / BN, M_TOK / BM), 256, 0, stream>>>(xb, wt, C, bias, out);
}

// Round 4
// 297.570 us; speedup vs baseline: 2.6670x; 1.5004x over previous
//
#include <hip/hip_runtime.h>
#include <hip/hip_bf16.h>
#include <stdint.h>

#define M_TOK 32768
#define DIM   1024
#define ODIM  1024
#define NEXP  4
#define TOPK  2
#define KTOT  4096          // NEXP * DIM (Wt row length)
#define MTILES 260          // ceil((32768 + 4*127)/128)
#define PERM_LEN (MTILES * 128)

typedef unsigned short u16;
typedef __bf16 bf16x8 __attribute__((ext_vector_type(8)));
typedef float  f32x4  __attribute__((ext_vector_type(4)));

__device__ inline u16 f2bf(float f) {
  union { float f; unsigned u; } v; v.f = f;
  unsigned u = v.u;
  unsigned r = u + 0x7FFFu + ((u >> 16) & 1u);
  return (u16)(r >> 16);
}

__device__ inline unsigned pack2(float lo, float hi) {
  return (unsigned)f2bf(lo) | ((unsigned)f2bf(hi) << 16);
}

__device__ inline void async16(const void* g, void* l) {
  __builtin_amdgcn_global_load_lds(
      (const __attribute__((address_space(1))) unsigned int*)g,
      (__attribute__((address_space(3))) unsigned int*)l, 16, 0, 0);
}

// ---- pre-pass 1: x fp32 -> bf16 ----
__global__ void cvt_x(const float4* __restrict__ x, uint4* __restrict__ xb, int n8) {
  int i = blockIdx.x * blockDim.x + threadIdx.x;
  int stride = gridDim.x * blockDim.x;
  for (; i < n8; i += stride) {
    float4 a = x[2 * i];
    float4 b = x[2 * i + 1];
    uint4 o;
    o.x = pack2(a.x, a.y); o.y = pack2(a.z, a.w);
    o.z = pack2(b.x, b.y); o.w = pack2(b.z, b.w);
    xb[i] = o;
  }
}

// ---- pre-pass 2: W (E*D=4096, O=1024) fp32 -> Wt (O=1024, E*D=4096) bf16 ----
__global__ void cvt_wt(const float* __restrict__ W, u16* __restrict__ Wt) {
  __shared__ float t[32][33];
  int kk0 = blockIdx.x * 32, n0 = blockIdx.y * 32;
  int tx = threadIdx.x, ty = threadIdx.y;  // block (32,8)
#pragma unroll
  for (int j = 0; j < 32; j += 8)
    t[ty + j][tx] = W[(size_t)(kk0 + ty + j) * ODIM + n0 + tx];
  __syncthreads();
#pragma unroll
  for (int j = 0; j < 32; j += 8)
    Wt[(size_t)(n0 + ty + j) * KTOT + kk0 + tx] = f2bf(t[tx][ty + j]);
}

// ---- sort pipeline: ctrl[0..7]=cnt(s,e), ctrl[8..15]=cursor/padded-offset ----
__global__ void init_ctrl(int* __restrict__ ctrl, int* __restrict__ perm0,
                          int* __restrict__ perm1) {
  int i = blockIdx.x * blockDim.x + threadIdx.x;
  if (i < 16) ctrl[i] = 0;
  for (int j = i; j < PERM_LEN; j += gridDim.x * blockDim.x) {
    perm0[j] = -1; perm1[j] = -1;
  }
}

__global__ void hist(const int* __restrict__ tki, int* __restrict__ ctrl) {
  __shared__ int h[8];
  int tid = threadIdx.x;
  if (tid < 8) h[tid] = 0;
  __syncthreads();
  int a = blockIdx.x * 256 + tid;   // assignment id, 65536 total
  int t = a >> 1, s = a & 1;
  int e = tki[2 * t + s] & 3;
  atomicAdd(&h[s * 4 + e], 1);
  __syncthreads();
  if (tid < 8) atomicAdd(&ctrl[tid], h[tid]);
}

__global__ void plan(int* __restrict__ ctrl) {
  if (threadIdx.x == 0 && blockIdx.x == 0) {
#pragma unroll
    for (int s = 0; s < 2; ++s) {
      int off = 0;
#pragma unroll
      for (int e = 0; e < 4; ++e) {
        ctrl[8 + s * 4 + e] = off;
        int c = ctrl[s * 4 + e];
        off += (c + 127) & ~127;
      }
    }
  }
}

__global__ void scatter(const int* __restrict__ tki, const float* __restrict__ ew,
                        int* __restrict__ ctrl,
                        int* __restrict__ perm0, float* __restrict__ wgt0,
                        int* __restrict__ perm1, float* __restrict__ wgt1) {
  __shared__ int h[8], gbase[8], cur[8];
  int tid = threadIdx.x;
  if (tid < 8) { h[tid] = 0; cur[tid] = 0; }
  __syncthreads();
  int a = blockIdx.x * 256 + tid;
  int t = a >> 1, s = a & 1;
  int e = tki[2 * t + s] & 3;
  float w = ew[2 * t + s];
  int se = s * 4 + e;
  atomicAdd(&h[se], 1);
  __syncthreads();
  if (tid < 8 && h[tid] > 0) gbase[tid] = atomicAdd(&ctrl[8 + tid], h[tid]);
  __syncthreads();
  int rank = atomicAdd(&cur[se], 1);
  int pos = gbase[se] + rank;
  if (s == 0) { perm0[pos] = t; wgt0[pos] = w; }
  else        { perm1[pos] = t; wgt1[pos] = w; }
}

// ---- grouped GEMM pass: out[t] (=|+=) w * (x_t @ W_e + b_e) ----
// 128x128 tile, 2x2 waves, 4x4 frags/wave, single accumulator.
// A rows gathered via perm (per-lane global addresses into global_load_lds).
template<bool ACCUM>
__global__ __launch_bounds__(256, 3) void moe_gemm(
    const u16* __restrict__ Xb,      // [M_TOK][DIM] bf16
    const u16* __restrict__ Wt,      // [ODIM][KTOT] bf16
    const int* __restrict__ perm,    // [PERM_LEN] gathered token ids (-1 pad)
    const float* __restrict__ wgt,   // [PERM_LEN] combine weights
    const int* __restrict__ tki,     // [M_TOK][2] expert ids
    const float* __restrict__ bias,  // [NEXP][ODIM] fp32
    float* __restrict__ out,         // [M_TOK][ODIM] fp32
    int slot)
{
  __shared__ __align__(16) u16 As[128 * 64];   // 16 KB
  __shared__ __align__(16) u16 Bs[128 * 64];   // 16 KB
  __shared__ int   rowsS[128];
  __shared__ float wgtS[128];

  const int mtile = blockIdx.y;
  const int base = mtile * 128;
  const int t0 = perm[base];
  if (t0 < 0) return;                       // fully-padding tile (uniform)
  const int e = tki[2 * t0 + slot] & 3;

  const int tid = threadIdx.x;
  if (tid < 128) { rowsS[tid] = perm[base + tid]; wgtS[tid] = wgt[base + tid]; }

  const int wid = tid >> 6, lane = tid & 63;
  const int bcol = blockIdx.x * 128;
  const int wr = wid >> 1, wc = wid & 1;    // wave tile 64x64
  const int fcol = bcol + wc * 64;

  f32x4 acc[4][4];
#pragma unroll
  for (int m = 0; m < 4; ++m)
#pragma unroll
    for (int n = 0; n < 4; ++n)
      acc[m][n] = (f32x4){0.f, 0.f, 0.f, 0.f};

  const int srow = lane >> 3;                // 0..7
  const int scol = ((lane & 7) ^ srow) * 8;  // pre-swizzled source col
  const int hi16 = (lane >> 4) * 16;
  const int swz  = (lane & 7) << 4;
  char* AsB = (char*)As;
  char* BsB = (char*)Bs;

  __syncthreads();                           // rowsS/wgtS ready

  // per-thread staging base pointers (4 A-chunks + 4 B-chunks per wave)
  const u16* aptr[4];
  const u16* bptr[4];
#pragma unroll
  for (int i = 0; i < 4; ++i) {
    int c = wid * 4 + i;
    int r = rowsS[c * 8 + srow];
    if (r < 0) r = 0;                        // pad row: stage row 0, discard later
    aptr[i] = Xb + (size_t)r * DIM + scol;
    bptr[i] = Wt + (size_t)(bcol + c * 8 + srow) * KTOT + e * DIM + scol;
  }

  for (int kt = 0; kt < DIM / 64; ++kt) {    // 16 K-steps
    __syncthreads();
#pragma unroll
    for (int i = 0; i < 4; ++i)
      async16(aptr[i] + kt * 64, &As[(wid * 4 + i) * 512]);
#pragma unroll
    for (int i = 0; i < 4; ++i)
      async16(bptr[i] + kt * 64, &Bs[(wid * 4 + i) * 512]);
    __syncthreads();
#pragma unroll
    for (int kk = 0; kk < 2; ++kk) {
      const int cb = (kk * 64 + hi16) ^ swz;
      bf16x8 af[4], bfr[4];
#pragma unroll
      for (int m = 0; m < 4; ++m) {
        int row = wr * 64 + m * 16 + (lane & 15);
        af[m] = *reinterpret_cast<const bf16x8*>(AsB + row * 128 + cb);
      }
#pragma unroll
      for (int n = 0; n < 4; ++n) {
        int row = wc * 64 + n * 16 + (lane & 15);
        bfr[n] = *reinterpret_cast<const bf16x8*>(BsB + row * 128 + cb);
      }
#pragma unroll
      for (int m = 0; m < 4; ++m)
#pragma unroll
        for (int n = 0; n < 4; ++n)
          acc[m][n] = __builtin_amdgcn_mfma_f32_16x16x32_bf16(af[m], bfr[n], acc[m][n], 0, 0, 0);
    }
  }

  // epilogue: per-row weight * (acc + bias), gathered store (RMW on pass 2)
  float bb[4];
#pragma unroll
  for (int n = 0; n < 4; ++n)
    bb[n] = bias[e * ODIM + fcol + n * 16 + (lane & 15)];

#pragma unroll
  for (int m = 0; m < 4; ++m) {
#pragma unroll
    for (int r = 0; r < 4; ++r) {
      int rl = wr * 64 + m * 16 + (lane >> 4) * 4 + r;
      int t = rowsS[rl];
      if (t < 0) continue;
      float w = wgtS[rl];
      size_t o = (size_t)t * ODIM + fcol + (lane & 15);
#pragma unroll
      for (int n = 0; n < 4; ++n) {
        float v = w * (acc[m][n][r] + bb[n]);
        if (ACCUM) out[o + n * 16] += v;
        else       out[o + n * 16] = v;
      }
    }
  }
}

extern "C" void kernel_launch(void* const* d_in, const int* in_sizes, int n_in,
                              void* d_out, int out_size, void* d_ws, size_t ws_size,
                              hipStream_t stream) {
  const float* x    = (const float*)d_in[0];
  const float* ew   = (const float*)d_in[1];
  const int*   tki  = (const int*)d_in[2];
  const float* W    = (const float*)d_in[3];
  const float* bias = (const float*)d_in[4];
  float* out = (float*)d_out;

  char* ws = (char*)d_ws;
  u16*   xb    = (u16*)ws;                               // 67,108,864 B
  u16*   wt    = (u16*)(ws + 67108864);                  //  8,388,608 B
  int*   ctrl  = (int*)(ws + 75497472);                  //        64 B
  int*   perm0 = (int*)(ws + 75497728);                  //   133,120 B
  float* wgt0  = (float*)(ws + 75630848);
  int*   perm1 = (int*)(ws + 75763968);
  float* wgt1  = (float*)(ws + 75897088);                // end 76,030,208

  init_ctrl<<<64, 256, 0, stream>>>(ctrl, perm0, perm1);
  cvt_x<<<4096, 256, 0, stream>>>((const float4*)x, (uint4*)xb, M_TOK * DIM / 8);
  cvt_wt<<<dim3(KTOT / 32, ODIM / 32), dim3(32, 8), 0, stream>>>(W, wt);
  hist<<<256, 256, 0, stream>>>(tki, ctrl);
  plan<<<1, 64, 0, stream>>>(ctrl);
  scatter<<<256, 256, 0, stream>>>(tki, ew, ctrl, perm0, wgt0, perm1, wgt1);
  moe_gemm<false><<<dim3(ODIM / 128, MTILES), 256, 0, stream>>>(
      xb, wt, perm0, wgt0, tki, bias, out, 0);
  moe_gemm<true><<<dim3(ODIM / 128, MTILES), 256, 0, stream>>>(
      xb, wt, perm1, wgt1, tki, bias, out, 1);
}

// Round 5
// 288.203 us; speedup vs baseline: 2.7536x; 1.0325x over previous
//
#include <hip/hip_runtime.h>
#include <hip/hip_bf16.h>
#include <stdint.h>

#define M_TOK 32768
#define DIM   1024
#define ODIM  1024
#define NEXP  4
#define TOPK  2
#define KTOT  4096          // NEXP * DIM (Wt row length)
#define MTILES 260          // ceil((32768 + 4*127)/128)
#define PERM_LEN (MTILES * 128)
#define GEMM_GRID (8 * 33 * 8)   // 8 xcd * ceil(260/8) mgroups * 8 nblk

typedef unsigned short u16;
typedef __bf16 bf16x8 __attribute__((ext_vector_type(8)));
typedef float  f32x4  __attribute__((ext_vector_type(4)));

__device__ inline u16 f2bf(float f) {
  union { float f; unsigned u; } v; v.f = f;
  unsigned u = v.u;
  unsigned r = u + 0x7FFFu + ((u >> 16) & 1u);
  return (u16)(r >> 16);
}

__device__ inline unsigned pack2(float lo, float hi) {
  return (unsigned)f2bf(lo) | ((unsigned)f2bf(hi) << 16);
}

__device__ inline void async16(const void* g, void* l) {
  __builtin_amdgcn_global_load_lds(
      (const __attribute__((address_space(1))) unsigned int*)g,
      (__attribute__((address_space(3))) unsigned int*)l, 16, 0, 0);
}

// ---- pre-pass 1: x fp32 -> bf16 ----
__global__ void cvt_x(const float4* __restrict__ x, uint4* __restrict__ xb, int n8) {
  int i = blockIdx.x * blockDim.x + threadIdx.x;
  int stride = gridDim.x * blockDim.x;
  for (; i < n8; i += stride) {
    float4 a = x[2 * i];
    float4 b = x[2 * i + 1];
    uint4 o;
    o.x = pack2(a.x, a.y); o.y = pack2(a.z, a.w);
    o.z = pack2(b.x, b.y); o.w = pack2(b.z, b.w);
    xb[i] = o;
  }
}

// ---- pre-pass 2: W (E*D=4096, O=1024) fp32 -> Wt (O=1024, E*D=4096) bf16 ----
__global__ void cvt_wt(const float* __restrict__ W, u16* __restrict__ Wt) {
  __shared__ float t[32][33];
  int kk0 = blockIdx.x * 32, n0 = blockIdx.y * 32;
  int tx = threadIdx.x, ty = threadIdx.y;  // block (32,8)
#pragma unroll
  for (int j = 0; j < 32; j += 8)
    t[ty + j][tx] = W[(size_t)(kk0 + ty + j) * ODIM + n0 + tx];
  __syncthreads();
#pragma unroll
  for (int j = 0; j < 32; j += 8)
    Wt[(size_t)(n0 + ty + j) * KTOT + kk0 + tx] = f2bf(t[tx][ty + j]);
}

// ---- sort pipeline: ctrl[0..7]=cnt(s,e), ctrl[8..15]=cursor/padded-offset ----
__global__ void init_ctrl(int* __restrict__ ctrl, int* __restrict__ perm0,
                          int* __restrict__ perm1) {
  int i = blockIdx.x * blockDim.x + threadIdx.x;
  if (i < 16) ctrl[i] = 0;
  for (int j = i; j < PERM_LEN; j += gridDim.x * blockDim.x) {
    perm0[j] = -1; perm1[j] = -1;
  }
}

__global__ void hist(const int* __restrict__ tki, int* __restrict__ ctrl) {
  __shared__ int h[8];
  int tid = threadIdx.x;
  if (tid < 8) h[tid] = 0;
  __syncthreads();
  int a = blockIdx.x * 256 + tid;   // assignment id, 65536 total
  int t = a >> 1, s = a & 1;
  int e = tki[2 * t + s] & 3;
  atomicAdd(&h[s * 4 + e], 1);
  __syncthreads();
  if (tid < 8) atomicAdd(&ctrl[tid], h[tid]);
}

__global__ void plan(int* __restrict__ ctrl) {
  if (threadIdx.x == 0 && blockIdx.x == 0) {
#pragma unroll
    for (int s = 0; s < 2; ++s) {
      int off = 0;
#pragma unroll
      for (int e = 0; e < 4; ++e) {
        ctrl[8 + s * 4 + e] = off;
        int c = ctrl[s * 4 + e];
        off += (c + 127) & ~127;
      }
    }
  }
}

__global__ void scatter(const int* __restrict__ tki, const float* __restrict__ ew,
                        int* __restrict__ ctrl,
                        int* __restrict__ perm0, float* __restrict__ wgt0,
                        int* __restrict__ perm1, float* __restrict__ wgt1) {
  __shared__ int h[8], gbase[8], cur[8];
  int tid = threadIdx.x;
  if (tid < 8) { h[tid] = 0; cur[tid] = 0; }
  __syncthreads();
  int a = blockIdx.x * 256 + tid;
  int t = a >> 1, s = a & 1;
  int e = tki[2 * t + s] & 3;
  float w = ew[2 * t + s];
  int se = s * 4 + e;
  atomicAdd(&h[se], 1);
  __syncthreads();
  if (tid < 8 && h[tid] > 0) gbase[tid] = atomicAdd(&ctrl[8 + tid], h[tid]);
  __syncthreads();
  int rank = atomicAdd(&cur[se], 1);
  int pos = gbase[se] + rank;
  if (s == 0) { perm0[pos] = t; wgt0[pos] = w; }
  else        { perm1[pos] = t; wgt1[pos] = w; }
}

// ---- grouped GEMM pass: out[t] (=|+=) w * (x_t @ W_e + b_e) ----
// 128x128 tile, 2x2 waves, 4x4 frags/wave, double-buffered LDS (2-phase
// pipeline: stage kt+1 before computing kt, one vmcnt-drain barrier per step).
// Linear grid remapped so the 8 N-blocks of one M-tile land on ONE XCD
// (hardware round-robins consecutive ids across 8 XCDs) -> A-panel L2 reuse.
template<bool ACCUM>
__global__ __launch_bounds__(256, 2) void moe_gemm(
    const u16* __restrict__ Xb,      // [M_TOK][DIM] bf16
    const u16* __restrict__ Wt,      // [ODIM][KTOT] bf16
    const int* __restrict__ perm,    // [PERM_LEN] gathered token ids (-1 pad)
    const float* __restrict__ wgt,   // [PERM_LEN] combine weights
    const int* __restrict__ tki,     // [M_TOK][2] expert ids
    const float* __restrict__ bias,  // [NEXP][ODIM] fp32
    float* __restrict__ out,         // [M_TOK][ODIM] fp32
    int slot)
{
  __shared__ __align__(16) u16 As[2][128 * 64];   // 2 x 16 KB
  __shared__ __align__(16) u16 Bs[2][128 * 64];   // 2 x 16 KB
  __shared__ int   rowsS[128];
  __shared__ float wgtS[128];

  // XCD-locality remap: d -> (xcd = d&7, slotid = d>>3); M-tile = xcd + 8*(slotid>>3)
  const int d = blockIdx.x;
  const int mtile = (d & 7) + ((d >> 6) << 3);
  const int nblk = (d >> 3) & 7;
  if (mtile >= MTILES) return;
  const int base = mtile * 128;
  const int t0 = perm[base];
  if (t0 < 0) return;                       // fully-padding tile (uniform)
  const int e = tki[2 * t0 + slot] & 3;

  const int tid = threadIdx.x;
  if (tid < 128) { rowsS[tid] = perm[base + tid]; wgtS[tid] = wgt[base + tid]; }

  const int wid = tid >> 6, lane = tid & 63;
  const int bcol = nblk * 128;
  const int wr = wid >> 1, wc = wid & 1;    // wave tile 64x64
  const int fcol = bcol + wc * 64;

  f32x4 acc[4][4];
#pragma unroll
  for (int m = 0; m < 4; ++m)
#pragma unroll
    for (int n = 0; n < 4; ++n)
      acc[m][n] = (f32x4){0.f, 0.f, 0.f, 0.f};

  const int srow = lane >> 3;                // 0..7
  const int scol = ((lane & 7) ^ srow) * 8;  // pre-swizzled source col
  const int hi16 = (lane >> 4) * 16;
  const int swz  = (lane & 7) << 4;

  __syncthreads();                           // rowsS/wgtS ready

  // per-thread staging base pointers (4 A-chunks + 4 B-chunks per wave)
  const u16* aptr[4];
  const u16* bptr[4];
#pragma unroll
  for (int i = 0; i < 4; ++i) {
    int c = wid * 4 + i;
    int r = rowsS[c * 8 + srow];
    if (r < 0) r = 0;                        // pad row: stage row 0, discard later
    aptr[i] = Xb + (size_t)r * DIM + scol;
    bptr[i] = Wt + (size_t)(bcol + c * 8 + srow) * KTOT + e * DIM + scol;
  }

  // prologue: stage kt=0 into buffer 0
#pragma unroll
  for (int i = 0; i < 4; ++i) {
    async16(aptr[i], &As[0][(wid * 4 + i) * 512]);
    async16(bptr[i], &Bs[0][(wid * 4 + i) * 512]);
  }
  __syncthreads();                           // drain vmcnt(0) + barrier

  for (int kt = 0; kt < DIM / 64; ++kt) {    // 16 K-steps
    const int cur = kt & 1;
    // issue next-tile prefetch BEFORE compute (latency hides under MFMA)
    if (kt + 1 < DIM / 64) {
#pragma unroll
      for (int i = 0; i < 4; ++i) {
        async16(aptr[i] + (kt + 1) * 64, &As[cur ^ 1][(wid * 4 + i) * 512]);
        async16(bptr[i] + (kt + 1) * 64, &Bs[cur ^ 1][(wid * 4 + i) * 512]);
      }
    }
    const char* AsB = (const char*)As[cur];
    const char* BsB = (const char*)Bs[cur];
#pragma unroll
    for (int kk = 0; kk < 2; ++kk) {
      const int cb = (kk * 64 + hi16) ^ swz;
      bf16x8 af[4], bfr[4];
#pragma unroll
      for (int m = 0; m < 4; ++m) {
        int row = wr * 64 + m * 16 + (lane & 15);
        af[m] = *reinterpret_cast<const bf16x8*>(AsB + row * 128 + cb);
      }
#pragma unroll
      for (int n = 0; n < 4; ++n) {
        int row = wc * 64 + n * 16 + (lane & 15);
        bfr[n] = *reinterpret_cast<const bf16x8*>(BsB + row * 128 + cb);
      }
#pragma unroll
      for (int m = 0; m < 4; ++m)
#pragma unroll
        for (int n = 0; n < 4; ++n)
          acc[m][n] = __builtin_amdgcn_mfma_f32_16x16x32_bf16(af[m], bfr[n], acc[m][n], 0, 0, 0);
    }
    // one barrier per K-step: drains prefetch writes (vmcnt 0) and protects
    // next iteration's overwrite of the buffer just computed.
    __syncthreads();
  }

  // epilogue: per-row weight * (acc + bias), gathered store (RMW on pass 2)
  float bb[4];
#pragma unroll
  for (int n = 0; n < 4; ++n)
    bb[n] = bias[e * ODIM + fcol + n * 16 + (lane & 15)];

#pragma unroll
  for (int m = 0; m < 4; ++m) {
#pragma unroll
    for (int r = 0; r < 4; ++r) {
      int rl = wr * 64 + m * 16 + (lane >> 4) * 4 + r;
      int t = rowsS[rl];
      if (t < 0) continue;
      float w = wgtS[rl];
      size_t o = (size_t)t * ODIM + fcol + (lane & 15);
#pragma unroll
      for (int n = 0; n < 4; ++n) {
        float v = w * (acc[m][n][r] + bb[n]);
        if (ACCUM) out[o + n * 16] += v;
        else       out[o + n * 16] = v;
      }
    }
  }
}

extern "C" void kernel_launch(void* const* d_in, const int* in_sizes, int n_in,
                              void* d_out, int out_size, void* d_ws, size_t ws_size,
                              hipStream_t stream) {
  const float* x    = (const float*)d_in[0];
  const float* ew   = (const float*)d_in[1];
  const int*   tki  = (const int*)d_in[2];
  const float* W    = (const float*)d_in[3];
  const float* bias = (const float*)d_in[4];
  float* out = (float*)d_out;

  char* ws = (char*)d_ws;
  u16*   xb    = (u16*)ws;                               // 67,108,864 B
  u16*   wt    = (u16*)(ws + 67108864);                  //  8,388,608 B
  int*   ctrl  = (int*)(ws + 75497472);                  //        64 B
  int*   perm0 = (int*)(ws + 75497728);                  //   133,120 B
  float* wgt0  = (float*)(ws + 75630848);
  int*   perm1 = (int*)(ws + 75763968);
  float* wgt1  = (float*)(ws + 75897088);                // end 76,030,208

  init_ctrl<<<64, 256, 0, stream>>>(ctrl, perm0, perm1);
  cvt_x<<<4096, 256, 0, stream>>>((const float4*)x, (uint4*)xb, M_TOK * DIM / 8);
  cvt_wt<<<dim3(KTOT / 32, ODIM / 32), dim3(32, 8), 0, stream>>>(W, wt);
  hist<<<256, 256, 0, stream>>>(tki, ctrl);
  plan<<<1, 64, 0, stream>>>(ctrl);
  scatter<<<256, 256, 0, stream>>>(tki, ew, ctrl, perm0, wgt0, perm1, wgt1);
  moe_gemm<false><<<GEMM_GRID, 256, 0, stream>>>(
      xb, wt, perm0, wgt0, tki, bias, out, 0);
  moe_gemm<true><<<GEMM_GRID, 256, 0, stream>>>(
      xb, wt, perm1, wgt1, tki, bias, out, 1);
}

// Round 7
// 240.291 us; speedup vs baseline: 3.3027x; 1.1994x over previous
//
#include <hip/hip_runtime.h>
#include <hip/hip_bf16.h>
#include <stdint.h>

#define M_TOK 32768
#define DIM   1024
#define ODIM  1024
#define NEXP  4
#define TOPK  2
#define KTOT  4096          // NEXP * DIM (Wt row length)
#define MTILES 260          // ceil((32768 + 4*127)/128)
#define PERM_LEN (MTILES * 128)
#define GEMM_GRID (8 * 33 * 8)   // 8 xcd * 33 mgroups * 8 nblk

typedef unsigned short u16;
typedef __bf16 bf16x8 __attribute__((ext_vector_type(8)));
typedef float  f32x4  __attribute__((ext_vector_type(4)));

__device__ inline u16 f2bf(float f) {
  union { float f; unsigned u; } v; v.f = f;
  unsigned u = v.u;
  unsigned r = u + 0x7FFFu + ((u >> 16) & 1u);
  return (u16)(r >> 16);
}

__device__ inline unsigned pack2(float lo, float hi) {
  return (unsigned)f2bf(lo) | ((unsigned)f2bf(hi) << 16);
}

__device__ inline void async16(const void* g, void* l) {
  __builtin_amdgcn_global_load_lds(
      (const __attribute__((address_space(1))) unsigned int*)g,
      (__attribute__((address_space(3))) unsigned int*)l, 16, 0, 0);
}

// ---- pre-pass 1: x fp32 -> bf16 ----
__global__ void cvt_x(const float4* __restrict__ x, uint4* __restrict__ xb, int n8) {
  int i = blockIdx.x * blockDim.x + threadIdx.x;
  int stride = gridDim.x * blockDim.x;
  for (; i < n8; i += stride) {
    float4 a = x[2 * i];
    float4 b = x[2 * i + 1];
    uint4 o;
    o.x = pack2(a.x, a.y); o.y = pack2(a.z, a.w);
    o.z = pack2(b.x, b.y); o.w = pack2(b.z, b.w);
    xb[i] = o;
  }
}

// ---- pre-pass 2: W (E*D=4096, O=1024) fp32 -> Wt (O=1024, E*D=4096) bf16 ----
__global__ void cvt_wt(const float* __restrict__ W, u16* __restrict__ Wt) {
  __shared__ float t[32][33];
  int kk0 = blockIdx.x * 32, n0 = blockIdx.y * 32;
  int tx = threadIdx.x, ty = threadIdx.y;  // block (32,8)
#pragma unroll
  for (int j = 0; j < 32; j += 8)
    t[ty + j][tx] = W[(size_t)(kk0 + ty + j) * ODIM + n0 + tx];
  __syncthreads();
#pragma unroll
  for (int j = 0; j < 32; j += 8)
    Wt[(size_t)(n0 + ty + j) * KTOT + kk0 + tx] = f2bf(t[tx][ty + j]);
}

// ---- sort pipeline: ctrl[0..7]=cnt(s,e), ctrl[8..15]=cursor/padded-offset ----
__global__ void init_ctrl(int* __restrict__ ctrl, int* __restrict__ perm0,
                          int* __restrict__ perm1) {
  int i = blockIdx.x * blockDim.x + threadIdx.x;
  if (i < 16) ctrl[i] = 0;
  for (int j = i; j < PERM_LEN; j += gridDim.x * blockDim.x) {
    perm0[j] = -1; perm1[j] = -1;
  }
}

__global__ void hist(const int* __restrict__ tki, int* __restrict__ ctrl) {
  __shared__ int h[8];
  int tid = threadIdx.x;
  if (tid < 8) h[tid] = 0;
  __syncthreads();
  int a = blockIdx.x * 256 + tid;   // assignment id, 65536 total
  int t = a >> 1, s = a & 1;
  int e = tki[2 * t + s] & 3;
  atomicAdd(&h[s * 4 + e], 1);
  __syncthreads();
  if (tid < 8) atomicAdd(&ctrl[tid], h[tid]);
}

__global__ void plan(int* __restrict__ ctrl) {
  if (threadIdx.x == 0 && blockIdx.x == 0) {
#pragma unroll
    for (int s = 0; s < 2; ++s) {
      int off = 0;
#pragma unroll
      for (int e = 0; e < 4; ++e) {
        ctrl[8 + s * 4 + e] = off;
        int c = ctrl[s * 4 + e];
        off += (c + 127) & ~127;
      }
    }
  }
}

__global__ void scatter(const int* __restrict__ tki, const float* __restrict__ ew,
                        int* __restrict__ ctrl,
                        int* __restrict__ perm0, float* __restrict__ wgt0,
                        int* __restrict__ perm1, float* __restrict__ wgt1) {
  __shared__ int h[8], gbase[8], cur[8];
  int tid = threadIdx.x;
  if (tid < 8) { h[tid] = 0; cur[tid] = 0; }
  __syncthreads();
  int a = blockIdx.x * 256 + tid;
  int t = a >> 1, s = a & 1;
  int e = tki[2 * t + s] & 3;
  float w = ew[2 * t + s];
  int se = s * 4 + e;
  atomicAdd(&h[se], 1);
  __syncthreads();
  if (tid < 8 && h[tid] > 0) gbase[tid] = atomicAdd(&ctrl[8 + tid], h[tid]);
  __syncthreads();
  int rank = atomicAdd(&cur[se], 1);
  int pos = gbase[se] + rank;
  if (s == 0) { perm0[pos] = t; wgt0[pos] = w; }
  else        { perm1[pos] = t; wgt1[pos] = w; }
}

// ---- grouped GEMM pass: out[t] (=|+=) w * (x_t @ W_e + b_e) ----
// 128x128 tile, 2x2 waves, 4x4 frags/wave, SINGLE-buffer LDS (32 KB ->
// 3 blocks/CU; TLP hides staging latency, m97-style). Grid remapped so the
// 8 N-blocks of one M-tile land on ONE XCD -> A-panel L2 reuse (T1).
template<bool ACCUM>
__global__ __launch_bounds__(256, 3) void moe_gemm(
    const u16* __restrict__ Xb,      // [M_TOK][DIM] bf16
    const u16* __restrict__ Wt,      // [ODIM][KTOT] bf16
    const int* __restrict__ perm,    // [PERM_LEN] gathered token ids (-1 pad)
    const float* __restrict__ wgt,   // [PERM_LEN] combine weights
    const int* __restrict__ tki,     // [M_TOK][2] expert ids
    const float* __restrict__ bias,  // [NEXP][ODIM] fp32
    float* __restrict__ out,         // [M_TOK][ODIM] fp32
    int slot)
{
  __shared__ __align__(16) u16 As[128 * 64];   // 16 KB
  __shared__ __align__(16) u16 Bs[128 * 64];   // 16 KB
  __shared__ int   rowsS[128];
  __shared__ float wgtS[128];

  // XCD-locality remap: consecutive blockIdx round-robin XCDs (d&7 = XCD);
  // all 8 nblk for one mtile share an XCD.
  const int d = blockIdx.x;
  const int mtile = (d & 7) + ((d >> 6) << 3);
  const int nblk = (d >> 3) & 7;
  if (mtile >= MTILES) return;
  const int base = mtile * 128;
  const int t0 = perm[base];
  if (t0 < 0) return;                       // fully-padding tile (uniform)
  const int e = tki[2 * t0 + slot] & 3;

  const int tid = threadIdx.x;
  if (tid < 128) { rowsS[tid] = perm[base + tid]; wgtS[tid] = wgt[base + tid]; }

  const int wid = tid >> 6, lane = tid & 63;
  const int bcol = nblk * 128;
  const int wr = wid >> 1, wc = wid & 1;    // wave tile 64x64
  const int fcol = bcol + wc * 64;

  f32x4 acc[4][4];
#pragma unroll
  for (int m = 0; m < 4; ++m)
#pragma unroll
    for (int n = 0; n < 4; ++n)
      acc[m][n] = (f32x4){0.f, 0.f, 0.f, 0.f};

  const int srow = lane >> 3;                // 0..7
  const int scol = ((lane & 7) ^ srow) * 8;  // pre-swizzled source col
  const int hi16 = (lane >> 4) * 16;
  const int swz  = (lane & 7) << 4;
  const char* AsB = (const char*)As;
  const char* BsB = (const char*)Bs;

  __syncthreads();                           // rowsS/wgtS ready

  // per-thread staging base pointers (4 A-chunks + 4 B-chunks per wave)
  const u16* aptr[4];
  const u16* bptr[4];
#pragma unroll
  for (int i = 0; i < 4; ++i) {
    int c = wid * 4 + i;
    int r = rowsS[c * 8 + srow];
    if (r < 0) r = 0;                        // pad row: stage row 0, discard later
    aptr[i] = Xb + (size_t)r * DIM + scol;
    bptr[i] = Wt + (size_t)(bcol + c * 8 + srow) * KTOT + e * DIM + scol;
  }

  for (int kt = 0; kt < DIM / 64; ++kt) {    // 16 K-steps
    __syncthreads();
#pragma unroll
    for (int i = 0; i < 4; ++i) {
      async16(aptr[i] + kt * 64, &As[(wid * 4 + i) * 512]);
      async16(bptr[i] + kt * 64, &Bs[(wid * 4 + i) * 512]);
    }
    __syncthreads();
#pragma unroll
    for (int kk = 0; kk < 2; ++kk) {
      const int cb = (kk * 64 + hi16) ^ swz;
      bf16x8 af[4], bfr[4];
#pragma unroll
      for (int m = 0; m < 4; ++m) {
        int row = wr * 64 + m * 16 + (lane & 15);
        af[m] = *reinterpret_cast<const bf16x8*>(AsB + row * 128 + cb);
      }
#pragma unroll
      for (int n = 0; n < 4; ++n) {
        int row = wc * 64 + n * 16 + (lane & 15);
        bfr[n] = *reinterpret_cast<const bf16x8*>(BsB + row * 128 + cb);
      }
#pragma unroll
      for (int m = 0; m < 4; ++m)
#pragma unroll
        for (int n = 0; n < 4; ++n)
          acc[m][n] = __builtin_amdgcn_mfma_f32_16x16x32_bf16(af[m], bfr[n], acc[m][n], 0, 0, 0);
    }
  }

  // epilogue: per-row weight * (acc + bias), gathered store (RMW on pass 2)
  float bb[4];
#pragma unroll
  for (int n = 0; n < 4; ++n)
    bb[n] = bias[e * ODIM + fcol + n * 16 + (lane & 15)];

#pragma unroll
  for (int m = 0; m < 4; ++m) {
#pragma unroll
    for (int r = 0; r < 4; ++r) {
      int rl = wr * 64 + m * 16 + (lane >> 4) * 4 + r;
      int t = rowsS[rl];
      if (t < 0) continue;
      float w = wgtS[rl];
      size_t o = (size_t)t * ODIM + fcol + (lane & 15);
#pragma unroll
      for (int n = 0; n < 4; ++n) {
        float v = w * (acc[m][n][r] + bb[n]);
        if (ACCUM) out[o + n * 16] += v;
        else       out[o + n * 16] = v;
      }
    }
  }
}

extern "C" void kernel_launch(void* const* d_in, const int* in_sizes, int n_in,
                              void* d_out, int out_size, void* d_ws, size_t ws_size,
                              hipStream_t stream) {
  const float* x    = (const float*)d_in[0];
  const float* ew   = (const float*)d_in[1];
  const int*   tki  = (const int*)d_in[2];
  const float* W    = (const float*)d_in[3];
  const float* bias = (const float*)d_in[4];
  float* out = (float*)d_out;

  char* ws = (char*)d_ws;
  u16*   xb    = (u16*)ws;                               // 67,108,864 B
  u16*   wt    = (u16*)(ws + 67108864);                  //  8,388,608 B
  int*   ctrl  = (int*)(ws + 75497472);                  //        64 B
  int*   perm0 = (int*)(ws + 75497728);                  //   133,120 B
  float* wgt0  = (float*)(ws + 75630848);
  int*   perm1 = (int*)(ws + 75763968);
  float* wgt1  = (float*)(ws + 75897088);                // end 76,030,208

  init_ctrl<<<64, 256, 0, stream>>>(ctrl, perm0, perm1);
  cvt_x<<<4096, 256, 0, stream>>>((const float4*)x, (uint4*)xb, M_TOK * DIM / 8);
  cvt_wt<<<dim3(KTOT / 32, ODIM / 32), dim3(32, 8), 0, stream>>>(W, wt);
  hist<<<256, 256, 0, stream>>>(tki, ctrl);
  plan<<<1, 64, 0, stream>>>(ctrl);
  scatter<<<256, 256, 0, stream>>>(tki, ew, ctrl, perm0, wgt0, perm1, wgt1);
  moe_gemm<false><<<GEMM_GRID, 256, 0, stream>>>(
      xb, wt, perm0, wgt0, tki, bias, out, 0);
  moe_gemm<true><<<GEMM_GRID, 256, 0, stream>>>(
      xb, wt, perm1, wgt1, tki, bias, out, 1);
}

// Round 10
// 239.725 us; speedup vs baseline: 3.3105x; 1.0024x over previous
//
#include <hip/hip_runtime.h>
#include <hip/hip_bf16.h>
#include <stdint.h>

#define M_TOK 32768
#define DIM   1024
#define ODIM  1024
#define NEXP  4
#define TOPK  2
#define KTOT  4096          // NEXP * DIM (Wt row length)
#define MTILES 260          // ceil((32768 + 4*127)/128)
#define PERM_LEN (MTILES * 128)
#define GEMM_GRID (8 * 33 * 8)   // 8 xcd * 33 mgroups * 8 nblk

typedef unsigned short u16;
typedef __bf16 bf16x8 __attribute__((ext_vector_type(8)));
typedef float  f32x4  __attribute__((ext_vector_type(4)));

__device__ inline u16 f2bf(float f) {
  union { float f; unsigned u; } v; v.f = f;
  unsigned u = v.u;
  unsigned r = u + 0x7FFFu + ((u >> 16) & 1u);
  return (u16)(r >> 16);
}

__device__ inline unsigned pack2(float lo, float hi) {
  return (unsigned)f2bf(lo) | ((unsigned)f2bf(hi) << 16);
}

__device__ inline void async16(const void* g, void* l) {
  __builtin_amdgcn_global_load_lds(
      (const __attribute__((address_space(1))) unsigned int*)g,
      (__attribute__((address_space(3))) unsigned int*)l, 16, 0, 0);
}

// ---- pre-pass 1: x fp32 -> bf16 ----
__global__ void cvt_x(const float4* __restrict__ x, uint4* __restrict__ xb, int n8) {
  int i = blockIdx.x * blockDim.x + threadIdx.x;
  int stride = gridDim.x * blockDim.x;
  for (; i < n8; i += stride) {
    float4 a = x[2 * i];
    float4 b = x[2 * i + 1];
    uint4 o;
    o.x = pack2(a.x, a.y); o.y = pack2(a.z, a.w);
    o.z = pack2(b.x, b.y); o.w = pack2(b.z, b.w);
    xb[i] = o;
  }
}

// ---- pre-pass 2: W (E*D=4096, O=1024) fp32 -> Wt (O=1024, E*D=4096) bf16 ----
__global__ void cvt_wt(const float* __restrict__ W, u16* __restrict__ Wt) {
  __shared__ float t[32][33];
  int kk0 = blockIdx.x * 32, n0 = blockIdx.y * 32;
  int tx = threadIdx.x, ty = threadIdx.y;  // block (32,8)
#pragma unroll
  for (int j = 0; j < 32; j += 8)
    t[ty + j][tx] = W[(size_t)(kk0 + ty + j) * ODIM + n0 + tx];
  __syncthreads();
#pragma unroll
  for (int j = 0; j < 32; j += 8)
    Wt[(size_t)(n0 + ty + j) * KTOT + kk0 + tx] = f2bf(t[tx][ty + j]);
}

// ---- sort pipeline: ctrl[0..7]=cnt(s,e), ctrl[8..15]=cursor/padded-offset ----
__global__ void init_ctrl(int* __restrict__ ctrl, int* __restrict__ perm0,
                          int* __restrict__ perm1) {
  int i = blockIdx.x * blockDim.x + threadIdx.x;
  if (i < 16) ctrl[i] = 0;
  for (int j = i; j < PERM_LEN; j += gridDim.x * blockDim.x) {
    perm0[j] = -1; perm1[j] = -1;
  }
}

__global__ void hist(const int* __restrict__ tki, int* __restrict__ ctrl) {
  __shared__ int h[8];
  int tid = threadIdx.x;
  if (tid < 8) h[tid] = 0;
  __syncthreads();
  int a = blockIdx.x * 256 + tid;   // assignment id, 65536 total
  int t = a >> 1, s = a & 1;
  int e = tki[2 * t + s] & 3;
  atomicAdd(&h[s * 4 + e], 1);
  __syncthreads();
  if (tid < 8) atomicAdd(&ctrl[tid], h[tid]);
}

__global__ void plan(int* __restrict__ ctrl) {
  if (threadIdx.x == 0 && blockIdx.x == 0) {
#pragma unroll
    for (int s = 0; s < 2; ++s) {
      int off = 0;
#pragma unroll
      for (int e = 0; e < 4; ++e) {
        ctrl[8 + s * 4 + e] = off;
        int c = ctrl[s * 4 + e];
        off += (c + 127) & ~127;
      }
    }
  }
}

__global__ void scatter(const int* __restrict__ tki, const float* __restrict__ ew,
                        int* __restrict__ ctrl,
                        int* __restrict__ perm0, float* __restrict__ wgt0,
                        int* __restrict__ perm1, float* __restrict__ wgt1) {
  __shared__ int h[8], gbase[8], cur[8];
  int tid = threadIdx.x;
  if (tid < 8) { h[tid] = 0; cur[tid] = 0; }
  __syncthreads();
  int a = blockIdx.x * 256 + tid;
  int t = a >> 1, s = a & 1;
  int e = tki[2 * t + s] & 3;
  float w = ew[2 * t + s];
  int se = s * 4 + e;
  atomicAdd(&h[se], 1);
  __syncthreads();
  if (tid < 8 && h[tid] > 0) gbase[tid] = atomicAdd(&ctrl[8 + tid], h[tid]);
  __syncthreads();
  int rank = atomicAdd(&cur[se], 1);
  int pos = gbase[se] + rank;
  if (s == 0) { perm0[pos] = t; wgt0[pos] = w; }
  else        { perm1[pos] = t; wgt1[pos] = w; }
}

// ---- grouped GEMM pass: out[t] (=|+=) w * (x_t @ W_e + b_e) ----
// 128x128 tile, 2x2 waves, 4x4 frags/wave, SINGLE-buffer LDS (32 KB).
// launch_bounds(256,4): 4 blocks/CU (LDS 4x33.8=135KB<=160; regs 60+64=124<=128)
// -> 16 waves/CU TLP hides staging latency. Grid remapped so the 8 N-blocks
// of one M-tile land on ONE XCD -> A-panel L2 reuse (T1).
template<bool ACCUM>
__global__ __launch_bounds__(256, 4) void moe_gemm(
    const u16* __restrict__ Xb,      // [M_TOK][DIM] bf16
    const u16* __restrict__ Wt,      // [ODIM][KTOT] bf16
    const int* __restrict__ perm,    // [PERM_LEN] gathered token ids (-1 pad)
    const float* __restrict__ wgt,   // [PERM_LEN] combine weights
    const int* __restrict__ tki,     // [M_TOK][2] expert ids
    const float* __restrict__ bias,  // [NEXP][ODIM] fp32
    float* __restrict__ out,         // [M_TOK][ODIM] fp32
    int slot)
{
  __shared__ __align__(16) u16 As[128 * 64];   // 16 KB
  __shared__ __align__(16) u16 Bs[128 * 64];   // 16 KB
  __shared__ int   rowsS[128];
  __shared__ float wgtS[128];

  // XCD-locality remap: consecutive blockIdx round-robin XCDs (d&7 = XCD);
  // all 8 nblk for one mtile share an XCD.
  const int d = blockIdx.x;
  const int mtile = (d & 7) + ((d >> 6) << 3);
  const int nblk = (d >> 3) & 7;
  if (mtile >= MTILES) return;
  const int base = mtile * 128;
  const int t0 = perm[base];
  if (t0 < 0) return;                       // fully-padding tile (uniform)
  const int e = tki[2 * t0 + slot] & 3;

  const int tid = threadIdx.x;
  if (tid < 128) { rowsS[tid] = perm[base + tid]; wgtS[tid] = wgt[base + tid]; }

  const int wid = tid >> 6, lane = tid & 63;
  const int bcol = nblk * 128;
  const int wr = wid >> 1, wc = wid & 1;    // wave tile 64x64
  const int fcol = bcol + wc * 64;

  f32x4 acc[4][4];
#pragma unroll
  for (int m = 0; m < 4; ++m)
#pragma unroll
    for (int n = 0; n < 4; ++n)
      acc[m][n] = (f32x4){0.f, 0.f, 0.f, 0.f};

  const int srow = lane >> 3;                // 0..7
  const int scol = ((lane & 7) ^ srow) * 8;  // pre-swizzled source col
  const int hi16 = (lane >> 4) * 16;
  const int swz  = (lane & 7) << 4;
  const char* AsB = (const char*)As;
  const char* BsB = (const char*)Bs;

  __syncthreads();                           // rowsS/wgtS ready

  // per-thread staging base pointers (4 A-chunks + 4 B-chunks per wave)
  const u16* aptr[4];
  const u16* bptr[4];
#pragma unroll
  for (int i = 0; i < 4; ++i) {
    int c = wid * 4 + i;
    int r = rowsS[c * 8 + srow];
    if (r < 0) r = 0;                        // pad row: stage row 0, discard later
    aptr[i] = Xb + (size_t)r * DIM + scol;
    bptr[i] = Wt + (size_t)(bcol + c * 8 + srow) * KTOT + e * DIM + scol;
  }

  for (int kt = 0; kt < DIM / 64; ++kt) {    // 16 K-steps
    __syncthreads();
#pragma unroll
    for (int i = 0; i < 4; ++i) {
      async16(aptr[i] + kt * 64, &As[(wid * 4 + i) * 512]);
      async16(bptr[i] + kt * 64, &Bs[(wid * 4 + i) * 512]);
    }
    __syncthreads();
#pragma unroll
    for (int kk = 0; kk < 2; ++kk) {
      const int cb = (kk * 64 + hi16) ^ swz;
      bf16x8 af[4], bfr[4];
#pragma unroll
      for (int m = 0; m < 4; ++m) {
        int row = wr * 64 + m * 16 + (lane & 15);
        af[m] = *reinterpret_cast<const bf16x8*>(AsB + row * 128 + cb);
      }
#pragma unroll
      for (int n = 0; n < 4; ++n) {
        int row = wc * 64 + n * 16 + (lane & 15);
        bfr[n] = *reinterpret_cast<const bf16x8*>(BsB + row * 128 + cb);
      }
#pragma unroll
      for (int m = 0; m < 4; ++m)
#pragma unroll
        for (int n = 0; n < 4; ++n)
          acc[m][n] = __builtin_amdgcn_mfma_f32_16x16x32_bf16(af[m], bfr[n], acc[m][n], 0, 0, 0);
    }
  }

  // epilogue: per-row weight * (acc + bias), gathered store (RMW on pass 2)
  float bb[4];
#pragma unroll
  for (int n = 0; n < 4; ++n)
    bb[n] = bias[e * ODIM + fcol + n * 16 + (lane & 15)];

#pragma unroll
  for (int m = 0; m < 4; ++m) {
#pragma unroll
    for (int r = 0; r < 4; ++r) {
      int rl = wr * 64 + m * 16 + (lane >> 4) * 4 + r;
      int t = rowsS[rl];
      if (t < 0) continue;
      float w = wgtS[rl];
      size_t o = (size_t)t * ODIM + fcol + (lane & 15);
#pragma unroll
      for (int n = 0; n < 4; ++n) {
        float v = w * (acc[m][n][r] + bb[n]);
        if (ACCUM) out[o + n * 16] += v;
        else       out[o + n * 16] = v;
      }
    }
  }
}

extern "C" void kernel_launch(void* const* d_in, const int* in_sizes, int n_in,
                              void* d_out, int out_size, void* d_ws, size_t ws_size,
                              hipStream_t stream) {
  const float* x    = (const float*)d_in[0];
  const float* ew   = (const float*)d_in[1];
  const int*   tki  = (const int*)d_in[2];
  const float* W    = (const float*)d_in[3];
  const float* bias = (const float*)d_in[4];
  float* out = (float*)d_out;

  char* ws = (char*)d_ws;
  u16*   xb    = (u16*)ws;                               // 67,108,864 B
  u16*   wt    = (u16*)(ws + 67108864);                  //  8,388,608 B
  int*   ctrl  = (int*)(ws + 75497472);                  //        64 B
  int*   perm0 = (int*)(ws + 75497728);                  //   133,120 B
  float* wgt0  = (float*)(ws + 75630848);
  int*   perm1 = (int*)(ws + 75763968);
  float* wgt1  = (float*)(ws + 75897088);                // end 76,030,208

  init_ctrl<<<64, 256, 0, stream>>>(ctrl, perm0, perm1);
  cvt_x<<<4096, 256, 0, stream>>>((const float4*)x, (uint4*)xb, M_TOK * DIM / 8);
  cvt_wt<<<dim3(KTOT / 32, ODIM / 32), dim3(32, 8), 0, stream>>>(W, wt);
  hist<<<256, 256, 0, stream>>>(tki, ctrl);
  plan<<<1, 64, 0, stream>>>(ctrl);
  scatter<<<256, 256, 0, stream>>>(tki, ew, ctrl, perm0, wgt0, perm1, wgt1);
  moe_gemm<false><<<GEMM_GRID, 256, 0, stream>>>(
      xb, wt, perm0, wgt0, tki, bias, out, 0);
  moe_gemm<true><<<GEMM_GRID, 256, 0, stream>>>(
      xb, wt, perm1, wgt1, tki, bias, out, 1);
}